// Round 13
// baseline (104.630 us; speedup 1.0000x reference)
//
#include <hip/hip_runtime.h>
#include <hip/hip_bf16.h>
#include <stdint.h>

#define THREADS 256
#define ROWS_PER_BLOCK 8
#define JSPLIT 2
#define EMB_ROWS 5050
#define PACK_OFF 65536   // byte offset of packed float4 array in d_ws

typedef _Float16 half2v __attribute__((ext_vector_type(2)));
typedef __fp16   fp16x2 __attribute__((ext_vector_type(2)));

__device__ __forceinline__ half2v pk(float a, float b) {
    fp16x2 r = __builtin_amdgcn_cvt_pkrtz(a, b);   // v_cvt_pkrtz_f16_f32
    return __builtin_bit_cast(half2v, r);
}
__device__ __forceinline__ half2v pkfma(half2v a, half2v b, half2v c) {
    return __builtin_elementwise_fma(a, b, c);     // v_pk_fma_f16
}

__global__ __launch_bounds__(THREADS) void pack_kernel(
    const float* __restrict__ coords, const float* __restrict__ charges,
    float4* __restrict__ pack, int n)
{
    const int i = blockIdx.x * THREADS + threadIdx.x;
    if (i < n)
        pack[i] = make_float4(coords[3 * i], coords[3 * i + 1],
                              coords[3 * i + 2], charges[i]);
}

// ABLATION ROUND. MODE: 0=FULL  1=NOMLP  2=NODIST  3=NOMEM
// Each variant writes its own partials region; only MODE 0 feeds d_out.
template <int MODE>
__global__ __launch_bounds__(THREADS) void ene_kernel(
    const float4* __restrict__ pack,
    const int*    __restrict__ atom_ix,
    const float*  __restrict__ emb,
    const float*  __restrict__ W1,
    const float*  __restrict__ b1,
    const float*  __restrict__ W2,
    const float*  __restrict__ b2,
    float* __restrict__ partials,
    int n_atoms)
{
    __shared__ uint32_t s_emb2[EMB_ROWS];
    for (int t = threadIdx.x; t < EMB_ROWS; t += THREADS) {
        const float e = emb[t];
        s_emb2[t] = __builtin_bit_cast(uint32_t, pk(e, e));
    }

    half2v A2[8], B2[8], C2[8], U0_2[8], U1_2[8], U2_2[8];
#pragma unroll
    for (int p = 0; p < 8; ++p) {
        A2[p]   = pk(W1[2 * p],      W1[2 * p + 1]);
        B2[p]   = pk(W1[16 + 2 * p], W1[16 + 2 * p + 1]);
        C2[p]   = pk(b1[2 * p],      b1[2 * p + 1]);
        U0_2[p] = pk(W2[3 * (2 * p) + 0], W2[3 * (2 * p + 1) + 0]);
        U1_2[p] = pk(W2[3 * (2 * p) + 1], W2[3 * (2 * p + 1) + 1]);
        U2_2[p] = pk(W2[3 * (2 * p) + 2], W2[3 * (2 * p + 1) + 2]);
    }
    const float bo0 = b2[0], bo1 = b2[1], bo2 = b2[2];

    const int rb   = blockIdx.x / JSPLIT;
    const int js   = blockIdx.x % JSPLIT;
    const int row0 = rb * ROWS_PER_BLOCK;
    const int jlen = n_atoms / JSPLIT;
    const int j0   = js * jlen;
    const int jend = j0 + jlen;

    float  xr[ROWS_PER_BLOCK], yr[ROWS_PER_BLOCK], zr[ROWS_PER_BLOCK];
    half2v qr2[ROWS_PER_BLOCK];
    int    brb4[ROWS_PER_BLOCK];
#pragma unroll
    for (int r = 0; r < ROWS_PER_BLOCK; ++r) {
        const int i = row0 + r;
        const float4 p = pack[i];
        xr[r] = p.x; yr[r] = p.y; zr[r] = p.z;
        qr2[r] = pk(p.w, p.w);
        const int a = atom_ix[i];
        brb4[r] = ((a * (a + 1)) >> 1) << 2;
    }
    __syncthreads();

    float cacc = 0.0f, ljacc = 0.0f;
    const half2v zero2 = (half2v)(_Float16)0.0f;
    const char* sbase = (const char*)s_emb2;

#pragma unroll 1
    for (int j = j0 + threadIdx.x; j < jend; j += THREADS) {
        float4 pj;
        int    aj;
        if constexpr (MODE != 3) {
            pj = pack[j];
            aj = atom_ix[j];
        } else {  // NOMEM: synthetic j-data (cheap VALU, no loads)
            pj = make_float4((float)(j & 7), (float)(j & 3), (float)(j & 1), 0.5f);
            aj = 0;
        }
        const half2v qj2 = pk(pj.w, pj.w);
        const int    ajb = aj << 2;

#pragma unroll
        for (int r = 0; r < ROWS_PER_BLOCK; ++r) {
            float rd;
            if constexpr (MODE != 2) {
                const float dx = pj.x - xr[r];
                const float dy = pj.y - yr[r];
                const float dz = pj.z - zr[r];
                const float sq = fmaf(dx, dx, fmaf(dy, dy, dz * dz));
                // diagonal: v_rsq_f32(0)=+inf, fmin(inf,10)=10 == reference
                rd = fminf(__builtin_amdgcn_rsqf(sq), 10.0f);
            } else {
                rd = 0.125f;  // NODIST
            }

            half2v e2;
            if constexpr (MODE != 3)
                e2 = *(const half2v*)(sbase + brb4[r] + ajb);
            else
                e2 = pk(0.5f, 0.5f);
            const half2v c2 = qr2[r] * qj2;

            float o0, o1, o2;
            if constexpr (MODE != 1) {
                o0 = bo0; o1 = bo1; o2 = bo2;
#pragma unroll
                for (int p = 0; p < 8; ++p) {
                    half2v t = pkfma(c2, B2[p], C2[p]);
                    t = pkfma(e2, A2[p], t);
                    t = __builtin_elementwise_max(t, zero2);
                    o0 = __builtin_amdgcn_fdot2(t, U0_2[p], o0, false);
                    o1 = __builtin_amdgcn_fdot2(t, U1_2[p], o1, false);
                    o2 = __builtin_amdgcn_fdot2(t, U2_2[p], o2, false);
                }
            } else {  // NOMLP: 2 ops, keeps e2/c2 (and the gather) live
                const half2v t = pkfma(e2, B2[0], c2);
                o0 = (float)t[0];
                o1 = (float)t[1];
                o2 = o0;
            }

            cacc = fmaf(o0, rd, cacc);
            const float sr  = o1 * rd;
            const float sr2 = sr * sr;
            const float sr6 = sr2 * sr2 * sr2;
            ljacc = fmaf(o2, fmaf(sr6, sr6, -sr6), ljacc);
        }
    }

#pragma unroll
    for (int off = 32; off > 0; off >>= 1) {
        cacc  += __shfl_down(cacc, off, 64);
        ljacc += __shfl_down(ljacc, off, 64);
    }
    __shared__ float s_c[THREADS / 64], s_l[THREADS / 64];
    const int wave = threadIdx.x >> 6;
    const int lane = threadIdx.x & 63;
    if (lane == 0) { s_c[wave] = cacc; s_l[wave] = ljacc; }
    __syncthreads();
    if (threadIdx.x == 0) {
        float ct = 0.0f, lt = 0.0f;
#pragma unroll
        for (int w = 0; w < THREADS / 64; ++w) { ct += s_c[w]; lt += s_l[w]; }
        partials[2 * blockIdx.x + 0] = ct;
        partials[2 * blockIdx.x + 1] = lt;
    }
}

__global__ __launch_bounds__(THREADS, 1) void energy_reduce_kernel(
    const float* __restrict__ partials, int nblocks,
    const float* __restrict__ bias, float* __restrict__ out)
{
    float ct = 0.0f, lt = 0.0f;
    for (int b = threadIdx.x; b < nblocks; b += THREADS) {
        ct += partials[2 * b + 0];
        lt += partials[2 * b + 1];
    }
#pragma unroll
    for (int off = 32; off > 0; off >>= 1) {
        ct += __shfl_down(ct, off, 64);
        lt += __shfl_down(lt, off, 64);
    }
    __shared__ float s_c[THREADS / 64], s_l[THREADS / 64];
    const int wave = threadIdx.x >> 6;
    const int lane = threadIdx.x & 63;
    if (lane == 0) { s_c[wave] = ct; s_l[wave] = lt; }
    __syncthreads();
    if (threadIdx.x == 0) {
        float c = 0.0f, l = 0.0f;
#pragma unroll
        for (int w = 0; w < THREADS / 64; ++w) { c += s_c[w]; l += s_l[w]; }
        out[0] = -c + 1.602e-19f * l + bias[0];
    }
}

extern "C" void kernel_launch(void* const* d_in, const int* in_sizes, int n_in,
                              void* d_out, int out_size, void* d_ws, size_t ws_size,
                              hipStream_t stream)
{
    const float* coords  = (const float*)d_in[0];
    const int*   atom_ix = (const int*)d_in[1];
    const float* charges = (const float*)d_in[2];
    const float* emb     = (const float*)d_in[3];
    const float* W1      = (const float*)d_in[4];
    const float* b1      = (const float*)d_in[5];
    const float* W2      = (const float*)d_in[6];
    const float* b2      = (const float*)d_in[7];
    const float* bias    = (const float*)d_in[8];

    float*  out      = (float*)d_out;
    float4* pack     = (float4*)((char*)d_ws + PACK_OFF);

    const int n       = in_sizes[1];                       // 4096 atoms
    const int nblocks = (n / ROWS_PER_BLOCK) * JSPLIT;     // 1024 blocks

    float* p0 = (float*)((char*)d_ws + 0);
    float* p1 = (float*)((char*)d_ws + 8192);
    float* p2 = (float*)((char*)d_ws + 16384);
    float* p3 = (float*)((char*)d_ws + 24576);

    pack_kernel<<<(n + THREADS - 1) / THREADS, THREADS, 0, stream>>>(
        coords, charges, pack, n);
    ene_kernel<0><<<nblocks, THREADS, 0, stream>>>(
        pack, atom_ix, emb, W1, b1, W2, b2, p0, n);
    ene_kernel<1><<<nblocks, THREADS, 0, stream>>>(
        pack, atom_ix, emb, W1, b1, W2, b2, p1, n);
    ene_kernel<2><<<nblocks, THREADS, 0, stream>>>(
        pack, atom_ix, emb, W1, b1, W2, b2, p2, n);
    ene_kernel<3><<<nblocks, THREADS, 0, stream>>>(
        pack, atom_ix, emb, W1, b1, W2, b2, p3, n);
    energy_reduce_kernel<<<1, THREADS, 0, stream>>>(p0, nblocks, bias, out);
}

// Round 14
// 48.476 us; speedup vs baseline: 2.1584x; 2.1584x over previous
//
#include <hip/hip_runtime.h>
#include <hip/hip_bf16.h>
#include <stdint.h>

#define THREADS 256
#define ROWS_PER_BLOCK 8
#define JSPLIT 4
#define EMB_ROWS 5050
#define PACK_OFF 65536   // byte offset of packed float4 array in d_ws

typedef _Float16 half2v __attribute__((ext_vector_type(2)));
typedef __fp16   fp16x2 __attribute__((ext_vector_type(2)));

__device__ __forceinline__ half2v pk(float a, float b) {
    fp16x2 r = __builtin_amdgcn_cvt_pkrtz(a, b);   // v_cvt_pkrtz_f16_f32
    return __builtin_bit_cast(half2v, r);
}
__device__ __forceinline__ half2v pkfma(half2v a, half2v b, half2v c) {
    return __builtin_elementwise_fma(a, b, c);     // v_pk_fma_f16
}

__global__ __launch_bounds__(THREADS) void pack_kernel(
    const float* __restrict__ coords, const float* __restrict__ charges,
    float4* __restrict__ pack, int n)
{
    const int i = blockIdx.x * THREADS + threadIdx.x;
    if (i < n)
        pack[i] = make_float4(coords[3 * i], coords[3 * i + 1],
                              coords[3 * i + 2], charges[i]);
}

// Each block: 8 rows x 1024-wide j-slice; each thread TWO j's per iteration
// (16 independent pair-streams) so dependent f16 chains fill each other's
// stall slots. R13 calibration: ~4 cyc/VALU-slot; gains come from busy%.
__global__ __launch_bounds__(THREADS) void energy_main_kernel(
    const float4* __restrict__ pack,
    const int*    __restrict__ atom_ix,
    const float*  __restrict__ emb,
    const float*  __restrict__ W1,
    const float*  __restrict__ b1,
    const float*  __restrict__ W2,
    const float*  __restrict__ b2,
    float* __restrict__ partials,
    int n_atoms)
{
    __shared__ uint32_t s_emb2[EMB_ROWS];
    for (int t = threadIdx.x; t < EMB_ROWS; t += THREADS) {
        const float e = emb[t];
        s_emb2[t] = __builtin_bit_cast(uint32_t, pk(e, e));
    }

    half2v A2[8], B2[8], C2[8], U0_2[8], U1_2[8], U2_2[8];
#pragma unroll
    for (int p = 0; p < 8; ++p) {
        A2[p]   = pk(W1[2 * p],      W1[2 * p + 1]);
        B2[p]   = pk(W1[16 + 2 * p], W1[16 + 2 * p + 1]);
        C2[p]   = pk(b1[2 * p],      b1[2 * p + 1]);
        U0_2[p] = pk(W2[3 * (2 * p) + 0], W2[3 * (2 * p + 1) + 0]);
        U1_2[p] = pk(W2[3 * (2 * p) + 1], W2[3 * (2 * p + 1) + 1]);
        U2_2[p] = pk(W2[3 * (2 * p) + 2], W2[3 * (2 * p + 1) + 2]);
    }
    const float bo0 = b2[0], bo1 = b2[1], bo2 = b2[2];

    const int rb   = blockIdx.x / JSPLIT;
    const int js   = blockIdx.x % JSPLIT;
    const int row0 = rb * ROWS_PER_BLOCK;
    const int jlen = n_atoms / JSPLIT;
    const int j0   = js * jlen;
    const int jend = j0 + jlen;

    float  xr[ROWS_PER_BLOCK], yr[ROWS_PER_BLOCK], zr[ROWS_PER_BLOCK];
    half2v qr2[ROWS_PER_BLOCK];
    int    brb4[ROWS_PER_BLOCK];
#pragma unroll
    for (int r = 0; r < ROWS_PER_BLOCK; ++r) {
        const int i = row0 + r;
        const float4 p = pack[i];
        xr[r] = p.x; yr[r] = p.y; zr[r] = p.z;
        qr2[r] = pk(p.w, p.w);
        const int a = atom_ix[i];
        brb4[r] = ((a * (a + 1)) >> 1) << 2;
    }
    __syncthreads();

    float cacc = 0.0f, ljacc = 0.0f;
    const half2v zero2 = (half2v)(_Float16)0.0f;
    const char* sbase = (const char*)s_emb2;

#pragma unroll 1
    for (int j = j0 + 2 * (int)threadIdx.x; j < jend; j += 2 * THREADS) {
        const float4 pj[2] = { pack[j], pack[j + 1] };
        const int2   ajv   = *(const int2*)&atom_ix[j];
        const int    ajb[2] = { ajv.x << 2, ajv.y << 2 };
        const half2v qj2[2] = { pk(pj[0].w, pj[0].w), pk(pj[1].w, pj[1].w) };

#pragma unroll
        for (int r = 0; r < ROWS_PER_BLOCK; ++r) {
            float rd[2], o0[2], o1[2], o2[2];
            half2v e2[2], c2[2];
#pragma unroll
            for (int u = 0; u < 2; ++u) {
                const float dx = pj[u].x - xr[r];
                const float dy = pj[u].y - yr[r];
                const float dz = pj[u].z - zr[r];
                const float sq = fmaf(dx, dx, fmaf(dy, dy, dz * dz));
                // diagonal: v_rsq_f32(0)=+inf, fmin(inf,10)=10 == reference
                rd[u] = fminf(__builtin_amdgcn_rsqf(sq), 10.0f);
                e2[u] = *(const half2v*)(sbase + brb4[r] + ajb[u]);
                c2[u] = qr2[r] * qj2[u];
                o0[u] = bo0; o1[u] = bo1; o2[u] = bo2;
            }

#pragma unroll
            for (int p = 0; p < 8; ++p) {
#pragma unroll
                for (int u = 0; u < 2; ++u) {
                    half2v t = pkfma(c2[u], B2[p], C2[p]);
                    t = pkfma(e2[u], A2[p], t);
                    t = __builtin_elementwise_max(t, zero2);
                    o0[u] = __builtin_amdgcn_fdot2(t, U0_2[p], o0[u], false);
                    o1[u] = __builtin_amdgcn_fdot2(t, U1_2[p], o1[u], false);
                    o2[u] = __builtin_amdgcn_fdot2(t, U2_2[p], o2[u], false);
                }
            }

#pragma unroll
            for (int u = 0; u < 2; ++u) {
                cacc = fmaf(o0[u], rd[u], cacc);
                const float sr  = o1[u] * rd[u];
                const float sr2 = sr * sr;
                const float sr6 = sr2 * sr2 * sr2;
                ljacc = fmaf(o2[u], fmaf(sr6, sr6, -sr6), ljacc);
            }
        }
    }

    // Deterministic in-block reduction: wave shuffle, then LDS across waves.
#pragma unroll
    for (int off = 32; off > 0; off >>= 1) {
        cacc  += __shfl_down(cacc, off, 64);
        ljacc += __shfl_down(ljacc, off, 64);
    }
    __shared__ float s_c[THREADS / 64], s_l[THREADS / 64];
    const int wave = threadIdx.x >> 6;
    const int lane = threadIdx.x & 63;
    if (lane == 0) { s_c[wave] = cacc; s_l[wave] = ljacc; }
    __syncthreads();
    if (threadIdx.x == 0) {
        float ct = 0.0f, lt = 0.0f;
#pragma unroll
        for (int w = 0; w < THREADS / 64; ++w) { ct += s_c[w]; lt += s_l[w]; }
        partials[2 * blockIdx.x + 0] = ct;
        partials[2 * blockIdx.x + 1] = lt;
    }
}

// Final reduction over block partials (fixed order -> deterministic).
__global__ __launch_bounds__(THREADS, 1) void energy_reduce_kernel(
    const float* __restrict__ partials, int nblocks,
    const float* __restrict__ bias, float* __restrict__ out)
{
    float ct = 0.0f, lt = 0.0f;
    for (int b = threadIdx.x; b < nblocks; b += THREADS) {
        ct += partials[2 * b + 0];
        lt += partials[2 * b + 1];
    }
#pragma unroll
    for (int off = 32; off > 0; off >>= 1) {
        ct += __shfl_down(ct, off, 64);
        lt += __shfl_down(lt, off, 64);
    }
    __shared__ float s_c[THREADS / 64], s_l[THREADS / 64];
    const int wave = threadIdx.x >> 6;
    const int lane = threadIdx.x & 63;
    if (lane == 0) { s_c[wave] = ct; s_l[wave] = lt; }
    __syncthreads();
    if (threadIdx.x == 0) {
        float c = 0.0f, l = 0.0f;
#pragma unroll
        for (int w = 0; w < THREADS / 64; ++w) { c += s_c[w]; l += s_l[w]; }
        // COULOMB_CONSTANT = -1, EV = 1.602e-19
        out[0] = -c + 1.602e-19f * l + bias[0];
    }
}

extern "C" void kernel_launch(void* const* d_in, const int* in_sizes, int n_in,
                              void* d_out, int out_size, void* d_ws, size_t ws_size,
                              hipStream_t stream)
{
    const float* coords  = (const float*)d_in[0];
    const int*   atom_ix = (const int*)d_in[1];
    const float* charges = (const float*)d_in[2];
    const float* emb     = (const float*)d_in[3];
    const float* W1      = (const float*)d_in[4];
    const float* b1      = (const float*)d_in[5];
    const float* W2      = (const float*)d_in[6];
    const float* b2      = (const float*)d_in[7];
    const float* bias    = (const float*)d_in[8];

    float*  out      = (float*)d_out;
    float*  partials = (float*)d_ws;
    float4* pack     = (float4*)((char*)d_ws + PACK_OFF);

    const int n       = in_sizes[1];                       // 4096 atoms
    const int nblocks = (n / ROWS_PER_BLOCK) * JSPLIT;     // 2048 blocks

    pack_kernel<<<(n + THREADS - 1) / THREADS, THREADS, 0, stream>>>(
        coords, charges, pack, n);
    energy_main_kernel<<<nblocks, THREADS, 0, stream>>>(
        pack, atom_ix, emb, W1, b1, W2, b2, partials, n);
    energy_reduce_kernel<<<1, THREADS, 0, stream>>>(partials, nblocks, bias, out);
}